// Round 2
// baseline (450.207 us; speedup 1.0000x reference)
//
#include <hip/hip_runtime.h>

// ---------- common types ----------
typedef float  f32x4  __attribute__((ext_vector_type(4)));
typedef short  bf16x8 __attribute__((ext_vector_type(8)));

#define MFMA16(a, b, c) __builtin_amdgcn_mfma_f32_16x16x32_bf16((a), (b), (c), 0, 0, 0)

__device__ __forceinline__ short f2bf(float f) {
    union { float f; unsigned u; } a; a.f = f;
    unsigned r = a.u + 0x7fffu + ((a.u >> 16) & 1u);  // RNE
    return (short)(r >> 16);
}
__device__ __forceinline__ float bf2f(unsigned short u) {
    union { unsigned u; float f; } a; a.u = ((unsigned)u) << 16; return a.f;
}

// sizes
#define Bb   8
#define Nn   1024
#define DIM  768
#define HH   12
#define HD   64
#define INNER 768
#define SCALE 0.125f

// ---------- prep kernels ----------
__global__ void cast_to_bf16(const float* __restrict__ in, short* __restrict__ out, int n4) {
    int i = blockIdx.x * 256 + threadIdx.x;
    if (i >= n4) return;
    float4 f = reinterpret_cast<const float4*>(in)[i];
    unsigned lo = (unsigned)(unsigned short)f2bf(f.x) | ((unsigned)(unsigned short)f2bf(f.y) << 16);
    unsigned hi = (unsigned)(unsigned short)f2bf(f.z) | ((unsigned)(unsigned short)f2bf(f.w) << 16);
    reinterpret_cast<uint2*>(out)[i] = make_uint2(lo, hi);
}

// wt[c][k] = w[k][c]; w is [rows=K][cols], wt is [cols][K]
__global__ void transpose_cast(const float* __restrict__ w, short* __restrict__ wt,
                               int rows, int cols) {
    int idx = blockIdx.x * 256 + threadIdx.x;
    if (idx >= rows * cols) return;
    int c = idx / rows;
    int k = idx - c * rows;
    wt[idx] = f2bf(w[k * cols + c]);
}

// ---------- GEMM: C[M,N] = A[M,K] @ Bt[N,K]^T ----------
// 128x128 block tile, 4 waves in 2x2, each wave 64x64 (4x4 of 16x16 mfma tiles), BK=32
// MODE 0: QKV epilogue -> scatter to qb [b,h,n,d], kb [b,h,n,d], vtb [b,h,d,n] (bf16)
// MODE 1: out-proj epilogue -> fp32 out + bias
template <int MODE>
__global__ __launch_bounds__(256, 2)
void gemm128(const short* __restrict__ A, const short* __restrict__ Bt, int K,
             short* __restrict__ qb, short* __restrict__ kb, short* __restrict__ vtb,
             float* __restrict__ outp, const float* __restrict__ bias) {
    __shared__ __align__(16) short As[128 * 40];
    __shared__ __align__(16) short Bs[128 * 40];

    const int tid  = threadIdx.x;
    const int lane = tid & 63, wv = tid >> 6;
    const int wrow = wv >> 1, wcol = wv & 1;
    const int quad = lane >> 4, l16 = lane & 15;
    const int m0 = blockIdx.y * 128, n0 = blockIdx.x * 128;

    const int srow = tid >> 1;
    const int soff = (tid & 1) * 16;

    f32x4 acc[4][4];
#pragma unroll
    for (int i = 0; i < 4; i++)
#pragma unroll
        for (int j = 0; j < 4; j++) acc[i][j] = (f32x4){0.f, 0.f, 0.f, 0.f};

    for (int kc = 0; kc < K; kc += 32) {
        const uint4 a0 = *reinterpret_cast<const uint4*>(A + (size_t)(m0 + srow) * K + kc + soff);
        const uint4 a1 = *reinterpret_cast<const uint4*>(A + (size_t)(m0 + srow) * K + kc + soff + 8);
        const uint4 b0 = *reinterpret_cast<const uint4*>(Bt + (size_t)(n0 + srow) * K + kc + soff);
        const uint4 b1 = *reinterpret_cast<const uint4*>(Bt + (size_t)(n0 + srow) * K + kc + soff + 8);
        __syncthreads();
        *reinterpret_cast<uint4*>(&As[srow * 40 + soff])     = a0;
        *reinterpret_cast<uint4*>(&As[srow * 40 + soff + 8]) = a1;
        *reinterpret_cast<uint4*>(&Bs[srow * 40 + soff])     = b0;
        *reinterpret_cast<uint4*>(&Bs[srow * 40 + soff + 8]) = b1;
        __syncthreads();

        bf16x8 af[4], bfr[4];
#pragma unroll
        for (int t = 0; t < 4; t++)
            af[t] = *reinterpret_cast<bf16x8*>(&As[(wrow * 64 + t * 16 + l16) * 40 + quad * 8]);
#pragma unroll
        for (int t = 0; t < 4; t++)
            bfr[t] = *reinterpret_cast<bf16x8*>(&Bs[(wcol * 64 + t * 16 + l16) * 40 + quad * 8]);
#pragma unroll
        for (int rt = 0; rt < 4; rt++)
#pragma unroll
            for (int ct = 0; ct < 4; ct++)
                acc[rt][ct] = MFMA16(af[rt], bfr[ct], acc[rt][ct]);
    }

    // epilogue: C/D layout col=lane&15, row=quad*4+reg
#pragma unroll
    for (int rt = 0; rt < 4; rt++) {
#pragma unroll
        for (int ct = 0; ct < 4; ct++) {
            const int c = n0 + wcol * 64 + ct * 16 + l16;
#pragma unroll
            for (int reg = 0; reg < 4; reg++) {
                const int r = m0 + wrow * 64 + rt * 16 + quad * 4 + reg;
                const float v = acc[rt][ct][reg];
                if (MODE == 0) {
                    const int b = r >> 10, n = r & 1023;
                    const int which = (c >= 1536) ? 2 : (c >= 768 ? 1 : 0);
                    const int cc = c - which * 768;
                    const int h = cc >> 6, d = cc & 63;
                    const int bh = b * HH + h;
                    const short bv = f2bf(v);
                    if (which == 0)      qb[(bh << 16) + (n << 6) + d] = bv;
                    else if (which == 1) kb[(bh << 16) + (n << 6) + d] = bv;
                    else                 vtb[(bh << 16) + (d << 10) + n] = bv;
                } else {
                    outp[(size_t)r * 768 + c] = v + bias[c];
                }
            }
        }
    }
}

// ---------- attention pass 1: softmax-over-heads denominator ----------
// One wave per (b, n16-tile, m64-chunk): 8*64*16 = 8192 waves, 2048 blocks.
// All 12 heads' S land at identical (lane,reg) C-layout positions -> the
// exp-sum over h is pure per-lane register math. ZERO LDS, ZERO barriers.
// Output: inv_den bf16 in raw (m16-tile, lane, reg) layout so pass 2 reads
// it back as one coalesced 8B load (same MFMA C-layout on both sides).
__global__ __launch_bounds__(256, 4)
void attn_den(const short* __restrict__ qb, const short* __restrict__ kb,
              short* __restrict__ invp) {
    const int tid = threadIdx.x, lane = tid & 63, wv = tid >> 6;
    const int quad = lane >> 4, l16 = lane & 15;
    const int widx = blockIdx.x * 4 + wv;       // 0..8191
    const int b  = widx >> 10;
    const int nt = (widx >> 4) & 63;
    const int mc = widx & 15;
    const int n0 = nt << 4, mbase = mc << 6;

    // Q A-frags for all 12 heads: row=l16 (n), k=quad*8+j (d)
    bf16x8 aq[12][2];
#pragma unroll
    for (int h = 0; h < 12; h++) {
        const short* qp = qb + ((b * HH + h) << 16) + ((n0 + l16) << 6) + quad * 8;
        aq[h][0] = *reinterpret_cast<const bf16x8*>(qp);
        aq[h][1] = *reinterpret_cast<const bf16x8*>(qp + 32);
    }

    const f32x4 z = (f32x4){0.f, 0.f, 0.f, 0.f};
    for (int ms = 0; ms < 4; ms++) {
        const int m0 = mbase + (ms << 4);
        f32x4 den = z;
#pragma unroll 4
        for (int h = 0; h < 12; h++) {
            const short* kp = kb + ((b * HH + h) << 16) + ((m0 + l16) << 6) + quad * 8;
            bf16x8 k0 = *reinterpret_cast<const bf16x8*>(kp);
            bf16x8 k1 = *reinterpret_cast<const bf16x8*>(kp + 32);
            f32x4 s = MFMA16(aq[h][0], k0, z);
            s = MFMA16(aq[h][1], k1, s);
#pragma unroll
            for (int reg = 0; reg < 4; reg++) den[reg] += __expf(s[reg] * SCALE);
        }
        ushort4 out;
        out.x = (unsigned short)f2bf(1.0f / den[0]);
        out.y = (unsigned short)f2bf(1.0f / den[1]);
        out.z = (unsigned short)f2bf(1.0f / den[2]);
        out.w = (unsigned short)f2bf(1.0f / den[3]);
        const int mt = m0 >> 4;  // global m16-tile index 0..63
        *reinterpret_cast<ushort4*>(&invp[(((b * 64 + nt) * 64 + mt) * 64 + lane) * 4]) = out;
    }
}

// ---------- attention pass 2: per-head recompute-S + PV ----------
// Block = (b, h, n64): 8*12*16 = 1536 blocks, 4 waves, wave w -> rows n64+16w.
// K/V staged in LDS once per block (shared by 4 waves). P transposed to
// A-layout through a wave-private LDS stash (no cross-wave sharing;
// __threadfence_block() orders the intra-wave cross-lane RAW).
__global__ __launch_bounds__(256, 4)
void attn_pv(const short* __restrict__ qb, const short* __restrict__ kb,
             const short* __restrict__ vtb, const short* __restrict__ invp,
             short* __restrict__ attn_out) {
    __shared__ __align__(16) short Ks[32 * 72];      // [m][d], pad to 72
    __shared__ __align__(16) short Vs[64 * 40];      // [d][m], pad to 40
    __shared__ __align__(16) short Ps[4][16 * 40];   // per-wave [n][m], pad to 40

    const int tid = threadIdx.x, lane = tid & 63, wv = tid >> 6;
    const int quad = lane >> 4, l16 = lane & 15;
    const int bid = blockIdx.x;
    const int b = bid / 192;            // 12*16
    const int r = bid - b * 192;
    const int h = r >> 4;
    const int nt64 = r & 15;
    const int n0 = (nt64 << 6) + (wv << 4);
    const int nt = n0 >> 4;
    const int bh = b * HH + h;

    // Q A-frag (row=l16 -> n, k=quad*8+j -> d)
    const short* qp = qb + (bh << 16) + ((n0 + l16) << 6) + quad * 8;
    const bf16x8 aq0 = *reinterpret_cast<const bf16x8*>(qp);
    const bf16x8 aq1 = *reinterpret_cast<const bf16x8*>(qp + 32);

    const f32x4 z = (f32x4){0.f, 0.f, 0.f, 0.f};
    f32x4 O[4];
#pragma unroll
    for (int i = 0; i < 4; i++) O[i] = z;

    // staging split: K 32 rows x 128B (8 thr/row), V 64 rows x 64B (4 thr/row)
    const int krow = tid >> 3, koff = (tid & 7) * 8;
    const int vrow = tid >> 2, voff = (tid & 3) * 8;

    for (int m0 = 0; m0 < Nn; m0 += 32) {
        const uint4 kreg = *reinterpret_cast<const uint4*>(kb + (bh << 16) + ((m0 + krow) << 6) + koff);
        const uint4 vreg = *reinterpret_cast<const uint4*>(vtb + (bh << 16) + (vrow << 10) + m0 + voff);
        __syncthreads();   // prior-iter LDS reads done before overwrite
        *reinterpret_cast<uint4*>(&Ks[krow * 72 + koff]) = kreg;
        *reinterpret_cast<uint4*>(&Vs[vrow * 40 + voff]) = vreg;
        __syncthreads();

        // S = Q K^T for two 16-m halves; P = exp(scale*S) * inv_den -> stash
#pragma unroll
        for (int mh = 0; mh < 2; mh++) {
            const bf16x8 k0 = *reinterpret_cast<bf16x8*>(&Ks[(mh * 16 + l16) * 72 + quad * 8]);
            const bf16x8 k1 = *reinterpret_cast<bf16x8*>(&Ks[(mh * 16 + l16) * 72 + quad * 8 + 32]);
            f32x4 s = MFMA16(aq0, k0, z);
            s = MFMA16(aq1, k1, s);
            const int mt = (m0 >> 4) + mh;
            const ushort4 iv = *reinterpret_cast<const ushort4*>(
                &invp[(((b * 64 + nt) * 64 + mt) * 64 + lane) * 4]);
            const float i0 = bf2f(iv.x), i1 = bf2f(iv.y), i2 = bf2f(iv.z), i3 = bf2f(iv.w);
            Ps[wv][(quad * 4 + 0) * 40 + mh * 16 + l16] = f2bf(__expf(s[0] * SCALE) * i0);
            Ps[wv][(quad * 4 + 1) * 40 + mh * 16 + l16] = f2bf(__expf(s[1] * SCALE) * i1);
            Ps[wv][(quad * 4 + 2) * 40 + mh * 16 + l16] = f2bf(__expf(s[2] * SCALE) * i2);
            Ps[wv][(quad * 4 + 3) * 40 + mh * 16 + l16] = f2bf(__expf(s[3] * SCALE) * i3);
        }
        __threadfence_block();  // intra-wave cross-lane RAW on Ps (no s_barrier needed)

        // PV: A-frag = P[n=l16][m=quad*8+j] covers full k=32 in one frag
        const bf16x8 pa = *reinterpret_cast<bf16x8*>(&Ps[wv][l16 * 40 + quad * 8]);
#pragma unroll
        for (int dch = 0; dch < 4; dch++) {
            const bf16x8 vf = *reinterpret_cast<bf16x8*>(&Vs[(dch * 16 + l16) * 40 + quad * 8]);
            O[dch] = MFMA16(pa, vf, O[dch]);
        }
    }

    // epilogue: O C-layout row=quad*4+reg (n), col=l16 (d within chunk)
#pragma unroll
    for (int dch = 0; dch < 4; dch++) {
        const int col = h * 64 + dch * 16 + l16;
#pragma unroll
        for (int reg = 0; reg < 4; reg++) {
            const int n = quad * 4 + reg;
            attn_out[(size_t)((b << 10) + n0 + n) * 768 + col] = f2bf(O[dch][reg]);
        }
    }
}

// ---------- launch ----------
extern "C" void kernel_launch(void* const* d_in, const int* in_sizes, int n_in,
                              void* d_out, int out_size, void* d_ws, size_t ws_size,
                              hipStream_t stream) {
    const float* x     = (const float*)d_in[0];
    const float* w_qkv = (const float*)d_in[1];
    const float* w_out = (const float*)d_in[2];
    const float* b_out = (const float*)d_in[3];
    float* out = (float*)d_out;

    // workspace carving (all bf16 as short)
    short* xb   = (short*)d_ws;                 // [8192][768]
    short* wT1  = xb  + 8192 * 768;             // [2304][768]
    short* wT2  = wT1 + 2304 * 768;             // [768][768]
    short* qb   = wT2 + 768 * 768;              // [b][h][n][d] = 96*1024*64
    short* kb   = qb  + 96 * 65536;
    short* vtb  = kb  + 96 * 65536;             // [b][h][d][n]
    short* attn = vtb + 96 * 65536;             // [8192][768]
    short* invp = attn + 8192 * 768;            // [b][nt][mt][lane][4] = 8*64*64*256

    cast_to_bf16<<<6144, 256, 0, stream>>>(x, xb, (8192 * 768) / 4);
    transpose_cast<<<(2304 * 768) / 256, 256, 0, stream>>>(w_qkv, wT1, 768, 2304);
    transpose_cast<<<(768 * 768) / 256, 256, 0, stream>>>(w_out, wT2, 768, 768);

    gemm128<0><<<dim3(2304 / 128, 8192 / 128), 256, 0, stream>>>(
        xb, wT1, 768, qb, kb, vtb, nullptr, nullptr);

    attn_den<<<2048, 256, 0, stream>>>(qb, kb, invp);
    attn_pv<<<1536, 256, 0, stream>>>(qb, kb, vtb, invp, attn);

    gemm128<1><<<dim3(768 / 128, 8192 / 128), 256, 0, stream>>>(
        attn, wT2, 768, nullptr, nullptr, nullptr, out, b_out);
}

// Round 3
// 312.825 us; speedup vs baseline: 1.4392x; 1.4392x over previous
//
#include <hip/hip_runtime.h>

// ---------- common types ----------
typedef float  f32x4  __attribute__((ext_vector_type(4)));
typedef short  bf16x8 __attribute__((ext_vector_type(8)));

#define MFMA16(a, b, c) __builtin_amdgcn_mfma_f32_16x16x32_bf16((a), (b), (c), 0, 0, 0)

__device__ __forceinline__ short f2bf(float f) {
    union { float f; unsigned u; } a; a.f = f;
    unsigned r = a.u + 0x7fffu + ((a.u >> 16) & 1u);  // RNE
    return (short)(r >> 16);
}
__device__ __forceinline__ float bf2f(unsigned short u) {
    union { unsigned u; float f; } a; a.u = ((unsigned)u) << 16; return a.f;
}

// sizes
#define Bb   8
#define Nn   1024
#define DIM  768
#define HH   12
#define HD   64
#define INNER 768
#define SCALE 0.125f

// ---------- prep kernels ----------
__global__ void cast_to_bf16(const float* __restrict__ in, short* __restrict__ out, int n4) {
    int i = blockIdx.x * 256 + threadIdx.x;
    if (i >= n4) return;
    float4 f = reinterpret_cast<const float4*>(in)[i];
    unsigned lo = (unsigned)(unsigned short)f2bf(f.x) | ((unsigned)(unsigned short)f2bf(f.y) << 16);
    unsigned hi = (unsigned)(unsigned short)f2bf(f.z) | ((unsigned)(unsigned short)f2bf(f.w) << 16);
    reinterpret_cast<uint2*>(out)[i] = make_uint2(lo, hi);
}

// wt[c][k] = w[k][c]; w is [rows=K][cols], wt is [cols][K]
__global__ void transpose_cast(const float* __restrict__ w, short* __restrict__ wt,
                               int rows, int cols) {
    int idx = blockIdx.x * 256 + threadIdx.x;
    if (idx >= rows * cols) return;
    int c = idx / rows;
    int k = idx - c * rows;
    wt[idx] = f2bf(w[k * cols + c]);
}

// ---------- GEMM: C[M,N] = A[M,K] @ Bt[N,K]^T ----------
template <int MODE>
__global__ __launch_bounds__(256, 2)
void gemm128(const short* __restrict__ A, const short* __restrict__ Bt, int K,
             short* __restrict__ qb, short* __restrict__ kb, short* __restrict__ vtb,
             float* __restrict__ outp, const float* __restrict__ bias) {
    __shared__ __align__(16) short As[128 * 40];
    __shared__ __align__(16) short Bs[128 * 40];

    const int tid  = threadIdx.x;
    const int lane = tid & 63, wv = tid >> 6;
    const int wrow = wv >> 1, wcol = wv & 1;
    const int quad = lane >> 4, l16 = lane & 15;
    const int m0 = blockIdx.y * 128, n0 = blockIdx.x * 128;

    const int srow = tid >> 1;
    const int soff = (tid & 1) * 16;

    f32x4 acc[4][4];
#pragma unroll
    for (int i = 0; i < 4; i++)
#pragma unroll
        for (int j = 0; j < 4; j++) acc[i][j] = (f32x4){0.f, 0.f, 0.f, 0.f};

    for (int kc = 0; kc < K; kc += 32) {
        const uint4 a0 = *reinterpret_cast<const uint4*>(A + (size_t)(m0 + srow) * K + kc + soff);
        const uint4 a1 = *reinterpret_cast<const uint4*>(A + (size_t)(m0 + srow) * K + kc + soff + 8);
        const uint4 b0 = *reinterpret_cast<const uint4*>(Bt + (size_t)(n0 + srow) * K + kc + soff);
        const uint4 b1 = *reinterpret_cast<const uint4*>(Bt + (size_t)(n0 + srow) * K + kc + soff + 8);
        __syncthreads();
        *reinterpret_cast<uint4*>(&As[srow * 40 + soff])     = a0;
        *reinterpret_cast<uint4*>(&As[srow * 40 + soff + 8]) = a1;
        *reinterpret_cast<uint4*>(&Bs[srow * 40 + soff])     = b0;
        *reinterpret_cast<uint4*>(&Bs[srow * 40 + soff + 8]) = b1;
        __syncthreads();

        bf16x8 af[4], bfr[4];
#pragma unroll
        for (int t = 0; t < 4; t++)
            af[t] = *reinterpret_cast<bf16x8*>(&As[(wrow * 64 + t * 16 + l16) * 40 + quad * 8]);
#pragma unroll
        for (int t = 0; t < 4; t++)
            bfr[t] = *reinterpret_cast<bf16x8*>(&Bs[(wcol * 64 + t * 16 + l16) * 40 + quad * 8]);
#pragma unroll
        for (int rt = 0; rt < 4; rt++)
#pragma unroll
            for (int ct = 0; ct < 4; ct++)
                acc[rt][ct] = MFMA16(af[rt], bfr[ct], acc[rt][ct]);
    }

    // epilogue: C/D layout col=lane&15, row=quad*4+reg
#pragma unroll
    for (int rt = 0; rt < 4; rt++) {
#pragma unroll
        for (int ct = 0; ct < 4; ct++) {
            const int c = n0 + wcol * 64 + ct * 16 + l16;
#pragma unroll
            for (int reg = 0; reg < 4; reg++) {
                const int r = m0 + wrow * 64 + rt * 16 + quad * 4 + reg;
                const float v = acc[rt][ct][reg];
                if (MODE == 0) {
                    const int b = r >> 10, n = r & 1023;
                    const int which = (c >= 1536) ? 2 : (c >= 768 ? 1 : 0);
                    const int cc = c - which * 768;
                    const int h = cc >> 6, d = cc & 63;
                    const int bh = b * HH + h;
                    const short bv = f2bf(v);
                    if (which == 0)      qb[(bh << 16) + (n << 6) + d] = bv;
                    else if (which == 1) kb[(bh << 16) + (n << 6) + d] = bv;
                    else                 vtb[(bh << 16) + (d << 10) + n] = bv;
                } else {
                    outp[(size_t)r * 768 + c] = v + bias[c];
                }
            }
        }
    }
}

// ---------- attention pass 1 v2: tiled denominator ----------
// Block = (b, n128, m128): 512 blocks, 4 waves in 2x2 (each 64x64).
// Per head: stage Q[h] 128x64 + K[h] 128x64 in LDS; waves accumulate
// den += exp(scale*S) in registers across h (same (lane,reg) every head).
// b = bid&7 -> all blocks of one b on one XCD; its Q+K slice (3.1 MB)
// fits that XCD's 4 MB L2.
__global__ __launch_bounds__(256, 2)
void attn_den2(const short* __restrict__ qb, const short* __restrict__ kb,
               short* __restrict__ invp) {
    __shared__ __align__(16) short Qs[128 * 72];
    __shared__ __align__(16) short Ksh[128 * 72];

    const int tid = threadIdx.x, lane = tid & 63, wv = tid >> 6;
    const int wrow = wv >> 1, wcol = wv & 1;
    const int quad = lane >> 4, l16 = lane & 15;
    const int bid = blockIdx.x;
    const int b = bid & 7;
    const int nmt = bid >> 3;            // 0..63
    const int n0 = (nmt >> 3) << 7;      // n128 base
    const int m0 = (nmt & 7) << 7;       // m128 base
    const int srow = tid >> 1;           // 0..127
    const int soff = (tid & 1) * 32;     // shorts (64B per thread)

    f32x4 den[4][4];
#pragma unroll
    for (int i = 0; i < 4; i++)
#pragma unroll
        for (int j = 0; j < 4; j++) den[i][j] = (f32x4){0.f, 0.f, 0.f, 0.f};
    const f32x4 z = (f32x4){0.f, 0.f, 0.f, 0.f};

    for (int h = 0; h < HH; h++) {
        const short* qp = qb + ((b * HH + h) << 16) + ((n0 + srow) << 6) + soff;
        const short* kp = kb + ((b * HH + h) << 16) + ((m0 + srow) << 6) + soff;
        uint4 qr[4], kr[4];
#pragma unroll
        for (int j = 0; j < 4; j++) {
            qr[j] = *reinterpret_cast<const uint4*>(qp + j * 8);
            kr[j] = *reinterpret_cast<const uint4*>(kp + j * 8);
        }
        __syncthreads();  // prev-iter frag reads done before overwrite
#pragma unroll
        for (int j = 0; j < 4; j++) {
            *reinterpret_cast<uint4*>(&Qs[srow * 72 + soff + j * 8])  = qr[j];
            *reinterpret_cast<uint4*>(&Ksh[srow * 72 + soff + j * 8]) = kr[j];
        }
        __syncthreads();

        bf16x8 aq[4][2], bk[4][2];
#pragma unroll
        for (int t = 0; t < 4; t++) {
            const int row = wrow * 64 + t * 16 + l16;
            aq[t][0] = *reinterpret_cast<bf16x8*>(&Qs[row * 72 + quad * 8]);
            aq[t][1] = *reinterpret_cast<bf16x8*>(&Qs[row * 72 + 32 + quad * 8]);
        }
#pragma unroll
        for (int t = 0; t < 4; t++) {
            const int row = wcol * 64 + t * 16 + l16;
            bk[t][0] = *reinterpret_cast<bf16x8*>(&Ksh[row * 72 + quad * 8]);
            bk[t][1] = *reinterpret_cast<bf16x8*>(&Ksh[row * 72 + 32 + quad * 8]);
        }
#pragma unroll
        for (int nt = 0; nt < 4; nt++)
#pragma unroll
            for (int mt = 0; mt < 4; mt++) {
                f32x4 s = MFMA16(aq[nt][0], bk[mt][0], z);
                s = MFMA16(aq[nt][1], bk[mt][1], s);
#pragma unroll
                for (int r = 0; r < 4; r++) den[nt][mt][r] += __expf(s[r] * SCALE);
            }
    }

    // write inv_den in raw (tile, lane, reg) C-layout
#pragma unroll
    for (int nt = 0; nt < 4; nt++)
#pragma unroll
        for (int mt = 0; mt < 4; mt++) {
            const int ntg = (n0 >> 4) + wrow * 4 + nt;
            const int mtg = (m0 >> 4) + wcol * 4 + mt;
            ushort4 o;
            o.x = (unsigned short)f2bf(1.0f / den[nt][mt][0]);
            o.y = (unsigned short)f2bf(1.0f / den[nt][mt][1]);
            o.z = (unsigned short)f2bf(1.0f / den[nt][mt][2]);
            o.w = (unsigned short)f2bf(1.0f / den[nt][mt][3]);
            *reinterpret_cast<ushort4*>(&invp[(((b * 64 + ntg) * 64 + mtg) * 64 + lane) * 4]) = o;
        }
}

// ---------- attention pass 2 v2: per-head recompute-S + PV ----------
// Block = (b, h, n128): 768 blocks (3/CU), 4 waves, wave = 32 n-rows.
// K/V double-buffered in LDS -> ONE barrier per m32-iter. P transposed
// through wave-private LDS stash (intra-wave, no barrier).
__global__ __launch_bounds__(256, 4)
void attn_pv2(const short* __restrict__ qb, const short* __restrict__ kb,
              const short* __restrict__ vtb, const short* __restrict__ invp,
              short* __restrict__ attn_out) {
    __shared__ __align__(16) short Ks[2][32 * 72];   // [m][d]
    __shared__ __align__(16) short Vs[2][64 * 40];   // [d][m]
    __shared__ __align__(16) short Ps[4][32 * 40];   // per-wave [n][m]

    const int tid = threadIdx.x, lane = tid & 63, wv = tid >> 6;
    const int quad = lane >> 4, l16 = lane & 15;
    const int bid = blockIdx.x;
    const int b = bid & 7;
    const int r = bid >> 3;              // 0..95
    const int n4 = r / 12;               // 0..7 (n128 tile)
    const int h = r - n4 * 12;
    const int nb = n4 << 7;
    const int bh = b * HH + h;

    // Q A-frags for 2 n16-tiles
    bf16x8 aq[2][2];
#pragma unroll
    for (int nt = 0; nt < 2; nt++) {
        const short* qp = qb + (bh << 16) + ((nb + wv * 32 + nt * 16 + l16) << 6) + quad * 8;
        aq[nt][0] = *reinterpret_cast<const bf16x8*>(qp);
        aq[nt][1] = *reinterpret_cast<const bf16x8*>(qp + 32);
    }

    const f32x4 z = (f32x4){0.f, 0.f, 0.f, 0.f};
    f32x4 O[2][4];
#pragma unroll
    for (int nt = 0; nt < 2; nt++)
#pragma unroll
        for (int d = 0; d < 4; d++) O[nt][d] = z;

    const int krow = tid >> 3, koff = (tid & 7) * 8;   // K: 32 rows x 128B
    const int vrow = tid >> 2, voff = (tid & 3) * 8;   // V: 64 rows x 64B

    // preload tile 0
    uint4 kreg = *reinterpret_cast<const uint4*>(kb + (bh << 16) + (krow << 6) + koff);
    uint4 vreg = *reinterpret_cast<const uint4*>(vtb + (bh << 16) + (vrow << 10) + voff);

    for (int it = 0; it < 32; it++) {
        const int p = it & 1;
        *reinterpret_cast<uint4*>(&Ks[p][krow * 72 + koff]) = kreg;
        *reinterpret_cast<uint4*>(&Vs[p][vrow * 40 + voff]) = vreg;
        __syncthreads();
        if (it < 31) {
            const int m1 = (it + 1) << 5;
            kreg = *reinterpret_cast<const uint4*>(kb + (bh << 16) + ((m1 + krow) << 6) + koff);
            vreg = *reinterpret_cast<const uint4*>(vtb + (bh << 16) + (vrow << 10) + m1 + voff);
        }
        const int m0 = it << 5;

        // S + P-stash for two m16-halves x two n-tiles
#pragma unroll
        for (int mh = 0; mh < 2; mh++) {
            const bf16x8 k0 = *reinterpret_cast<bf16x8*>(&Ks[p][(mh * 16 + l16) * 72 + quad * 8]);
            const bf16x8 k1 = *reinterpret_cast<bf16x8*>(&Ks[p][(mh * 16 + l16) * 72 + quad * 8 + 32]);
            const int mt = (m0 >> 4) + mh;
#pragma unroll
            for (int nt = 0; nt < 2; nt++) {
                f32x4 s = MFMA16(aq[nt][0], k0, z);
                s = MFMA16(aq[nt][1], k1, s);
                const int ntg = (nb >> 4) + wv * 2 + nt;
                const ushort4 iv = *reinterpret_cast<const ushort4*>(
                    &invp[(((b * 64 + ntg) * 64 + mt) * 64 + lane) * 4]);
                Ps[wv][(nt * 16 + quad * 4 + 0) * 40 + mh * 16 + l16] = f2bf(__expf(s[0] * SCALE) * bf2f(iv.x));
                Ps[wv][(nt * 16 + quad * 4 + 1) * 40 + mh * 16 + l16] = f2bf(__expf(s[1] * SCALE) * bf2f(iv.y));
                Ps[wv][(nt * 16 + quad * 4 + 2) * 40 + mh * 16 + l16] = f2bf(__expf(s[2] * SCALE) * bf2f(iv.z));
                Ps[wv][(nt * 16 + quad * 4 + 3) * 40 + mh * 16 + l16] = f2bf(__expf(s[3] * SCALE) * bf2f(iv.w));
            }
        }
        __threadfence_block();  // intra-wave cross-lane RAW on Ps

        // PV
        bf16x8 pa[2];
#pragma unroll
        for (int nt = 0; nt < 2; nt++)
            pa[nt] = *reinterpret_cast<bf16x8*>(&Ps[wv][(nt * 16 + l16) * 40 + quad * 8]);
#pragma unroll
        for (int dch = 0; dch < 4; dch++) {
            const bf16x8 vf = *reinterpret_cast<bf16x8*>(&Vs[p][(dch * 16 + l16) * 40 + quad * 8]);
#pragma unroll
            for (int nt = 0; nt < 2; nt++)
                O[nt][dch] = MFMA16(pa[nt], vf, O[nt][dch]);
        }
    }

    // epilogue
#pragma unroll
    for (int nt = 0; nt < 2; nt++)
#pragma unroll
        for (int dch = 0; dch < 4; dch++) {
            const int col = h * 64 + dch * 16 + l16;
#pragma unroll
            for (int reg = 0; reg < 4; reg++) {
                const int n = nb + wv * 32 + nt * 16 + quad * 4 + reg;
                attn_out[(size_t)((b << 10) + n) * 768 + col] = f2bf(O[nt][dch][reg]);
            }
        }
}

// ---------- launch ----------
extern "C" void kernel_launch(void* const* d_in, const int* in_sizes, int n_in,
                              void* d_out, int out_size, void* d_ws, size_t ws_size,
                              hipStream_t stream) {
    const float* x     = (const float*)d_in[0];
    const float* w_qkv = (const float*)d_in[1];
    const float* w_out = (const float*)d_in[2];
    const float* b_out = (const float*)d_in[3];
    float* out = (float*)d_out;

    short* xb   = (short*)d_ws;                 // [8192][768]
    short* wT1  = xb  + 8192 * 768;             // [2304][768]
    short* wT2  = wT1 + 2304 * 768;             // [768][768]
    short* qb   = wT2 + 768 * 768;              // [b][h][n][d]
    short* kb   = qb  + 96 * 65536;
    short* vtb  = kb  + 96 * 65536;             // [b][h][d][n]
    short* attn = vtb + 96 * 65536;             // [8192][768]
    short* invp = attn + 8192 * 768;            // [b][nt][mt][lane][4]

    cast_to_bf16<<<6144, 256, 0, stream>>>(x, xb, (8192 * 768) / 4);
    transpose_cast<<<(2304 * 768) / 256, 256, 0, stream>>>(w_qkv, wT1, 768, 2304);
    transpose_cast<<<(768 * 768) / 256, 256, 0, stream>>>(w_out, wT2, 768, 768);

    gemm128<0><<<dim3(2304 / 128, 8192 / 128), 256, 0, stream>>>(
        xb, wT1, 768, qb, kb, vtb, nullptr, nullptr);

    attn_den2<<<512, 256, 0, stream>>>(qb, kb, invp);
    attn_pv2<<<768, 256, 0, stream>>>(qb, kb, vtb, invp, attn);

    gemm128<1><<<dim3(768 / 128, 8192 / 128), 256, 0, stream>>>(
        attn, wT2, 768, nullptr, nullptr, nullptr, out, b_out);
}